// Round 2
// baseline (584.859 us; speedup 1.0000x reference)
//
#include <hip/hip_runtime.h>
#include <math.h>

// Radial NUFFT + Pipe-Menon density compensation, MI355X (gfx950).
// bf16 MFMA (16x16x32), 2-term hi/lo split (3 products). Round 16: adj_gemm
// restructured BARRIER-FREE: no LDS, no global_load_lds DMA, no s_barrier.
// Each wave independently global-loads its 8 MFMA fragments per chunk
// (16B/lane coalesced, fragment-ordered global layout) with a named cur/nxt
// software pipeline -> compiler-counted vmcnt, stalls hidden by 16 waves/CU
// TLP instead of barrier-coupled blocks. r15 showed the LDS round-trip
// (DMA + ds_read + 2 barriers/chunk at ~2 blocks/CU) was the stall: all
// pipes <30% busy at 50us vs 15.5us MFMA floor.

#define MTOT 36864      // N_SHOTS*N_SAMPLES == NPIX*NPIX
#define NPIX 192
#define SPLITS 128
#define MPS (MTOT / SPLITS)     // 288 m per split
#define ADJ_CHUNKS (MPS / 16)   // 18 chunks of 16 m per split
#define PG 4                    // partial output images

typedef __attribute__((ext_vector_type(8))) short s16x8;
typedef __attribute__((ext_vector_type(4))) float f32x4;
typedef __attribute__((ext_vector_type(4))) unsigned u32x4;

__device__ __forceinline__ f32x4 mfma_bf16(u32x4 a, u32x4 b, f32x4 c) {
    return __builtin_amdgcn_mfma_f32_16x16x32_bf16(
        __builtin_bit_cast(s16x8, a), __builtin_bit_cast(s16x8, b), c, 0, 0, 0);
}

// Split (a,b) into packed bf16 pairs: hi = (bf16(a) | bf16(b)<<16), lo = residuals.
__device__ __forceinline__ void split_pk(float a, float b, unsigned &hi, unsigned &lo) {
    const unsigned ua = __float_as_uint(a), ub = __float_as_uint(b);
    const unsigned ha = (ua + 0x8000u) & 0xffff0000u;
    const unsigned hb = (ub + 0x8000u) & 0xffff0000u;
    hi = (ha >> 16) | hb;
    const float la = a - __uint_as_float(ha);
    const float lb = b - __uint_as_float(hb);
    lo = ((__float_as_uint(la) + 0x8000u) >> 16) |
         ((__float_as_uint(lb) + 0x8000u) & 0xffff0000u);
}

// k split into 12-bit hi + residual so kh*p (p integer, |p|<=96) is EXACT in fp32.
__device__ __forceinline__ void ksplit(float k, float &kh, float &kl) {
    kh = __uint_as_float(__float_as_uint(k) & 0xfffff000u);
    kl = k - kh;
}
__device__ __forceinline__ float redphase(float kh, float kl, float p) {
    float r = kh * p;
    r -= rintf(r);
    r = fmaf(kl, p, r);
    return r;                   // revolutions, |r| <= ~0.512
}
__device__ __forceinline__ unsigned rot16(unsigned v) {
    return __builtin_amdgcn_alignbit(v, v, 16);
}

// ---------------------------------------------------------------------------
// Precompute packed B phasor (cos, -sin) hi/lo, chunk-contiguous, PLAIN layout
// (no bank swizzle -- adj_gemm now reads fragments directly from global):
// PS[mc][plane][c(192)][mi(16)].
__global__ void precompP_k(const float* __restrict__ traj, const int comp,
                           unsigned* __restrict__ PS) {
    const int m = blockIdx.x * 256 + threadIdx.x;
    const int c = blockIdx.y;
    float kh, kl; ksplit(traj[2 * m + comp], kh, kl);
    const float ph = redphase(kh, kl, (float)(c - 96));
    const float co = __builtin_amdgcn_cosf(ph);
    const float si = __builtin_amdgcn_sinf(ph);
    unsigned h, l; split_pk(co, -si, h, l);
    const int mc = m >> 4, mi = m & 15;
    PS[(size_t)mc * 6144 + c * 16 + mi]        = h;
    PS[(size_t)mc * 6144 + 3072 + c * 16 + mi] = l;
}

// E[m,x] = conj(A[m,x]) * d[m], packed bf16 hi/lo, same plain layout.
__global__ void ebuild_k(const float* __restrict__ traj,
                         const float* __restrict__ dr, const float* __restrict__ di,
                         unsigned* __restrict__ ES) {
    const int m = blockIdx.x * 256 + threadIdx.x;
    const int c = blockIdx.y;                        // x coordinate
    float kh, kl; ksplit(traj[2 * m], kh, kl);
    const float ph = redphase(kh, kl, (float)(c - 96));
    const float co = __builtin_amdgcn_cosf(ph);
    const float si = __builtin_amdgcn_sinf(ph);
    const float dr_ = dr[m], di_ = di[m];
    const float Er = co * dr_ - si * di_;
    const float Ei = co * di_ + si * dr_;
    unsigned h, l; split_pk(Er, Ei, h, l);
    const int mc = m >> 4, mi = m & 15;
    ES[(size_t)mc * 6144 + c * 16 + mi]        = h;
    ES[(size_t)mc * 6144 + 3072 + c * 16 + mi] = l;
}

__global__ void winit_k(float* __restrict__ wr, float* __restrict__ wi) {
    const int m = blockIdx.x * 256 + threadIdx.x;
    wr[m] = 1.f; wi[m] = 0.f;
}

// ---------------------------------------------------------------------------
// Adjoint pure GEMM: out[x,y] += sum_m E[m,x]*conj(B[m,y]).
// Barrier-free: each wave owns a 32x32 output tile and loads its own
// fragments straight from global (L1/L2/L3 serve the reuse). Per chunk per
// wave: 8 x global_load_dwordx4 (16B/lane, each covering a contiguous 1KB
// fragment) + 24 MFMA. cur/nxt named-variable pipeline: nxt's 8 loads stay
// in flight while cur computes (in-order vmcnt -> compiler emits vmcnt(8)).
__global__ __launch_bounds__(256, 4) void adj_gemm_k(
    const unsigned* __restrict__ ES, const unsigned* __restrict__ BS,
    float* __restrict__ outP)
{
    const int tid = threadIdx.x;
    const int lane = tid & 63, wid = tid >> 6;     // wid 0..3
    const int l15 = lane & 15, qd = lane >> 4;
    const int L = blockIdx.x;                      // 0..1151, XCD swizzle
    const int xcd = L & 7, j = L >> 3;
    const int s = xcd * (SPLITS / 8) + j / 9;      // split 0..127
    const int tile = j % 9;
    const int bx = tile % 3, by = tile / 3;
    const int wi = wid & 1, wj = wid >> 1;
    const int x0 = bx * 64 + wi * 32, y0 = by * 64 + wj * 32;
    float* outRe = outP + (size_t)(s & (PG - 1)) * (2 * MTOT);
    float* outIm = outRe + MTOT;

    // lane word-offsets of the 16B fragment loads within a chunk
    int eo0, eo1, bo0, bo1;
    eo0 = (x0 + l15) * 16 + qd * 4;
    eo1 = (x0 + 16 + l15) * 16 + qd * 4;
    bo0 = (y0 + l15) * 16 + qd * 4;
    bo1 = (y0 + 16 + l15) * 16 + qd * 4;

    const unsigned* Ech = ES + (size_t)(s * ADJ_CHUNKS) * 6144;
    const unsigned* Bch = BS + (size_t)(s * ADJ_CHUNKS) * 6144;

    f32x4 accRe[2][2], accIm[2][2];
    #pragma unroll
    for (int i = 0; i < 2; ++i)
        #pragma unroll
        for (int j2 = 0; j2 < 2; ++j2) {
            accRe[i][j2] = (f32x4){0.f, 0.f, 0.f, 0.f};
            accIm[i][j2] = (f32x4){0.f, 0.f, 0.f, 0.f};
        }

    // chunk 0 fragments
    u32x4 cEh0 = *(const u32x4*)(Ech + eo0);
    u32x4 cEh1 = *(const u32x4*)(Ech + eo1);
    u32x4 cEl0 = *(const u32x4*)(Ech + 3072 + eo0);
    u32x4 cEl1 = *(const u32x4*)(Ech + 3072 + eo1);
    u32x4 cPh0 = *(const u32x4*)(Bch + bo0);
    u32x4 cPh1 = *(const u32x4*)(Bch + bo1);
    u32x4 cPl0 = *(const u32x4*)(Bch + 3072 + bo0);
    u32x4 cPl1 = *(const u32x4*)(Bch + 3072 + bo1);

    for (int ch = 0; ch < ADJ_CHUNKS - 1; ++ch) {
        Ech += 6144; Bch += 6144;
        // issue next chunk's 8 loads (stay in flight across cur's compute)
        u32x4 nEh0 = *(const u32x4*)(Ech + eo0);
        u32x4 nEh1 = *(const u32x4*)(Ech + eo1);
        u32x4 nEl0 = *(const u32x4*)(Ech + 3072 + eo0);
        u32x4 nEl1 = *(const u32x4*)(Ech + 3072 + eo1);
        u32x4 nPh0 = *(const u32x4*)(Bch + bo0);
        u32x4 nPh1 = *(const u32x4*)(Bch + bo1);
        u32x4 nPl0 = *(const u32x4*)(Bch + 3072 + bo0);
        u32x4 nPl1 = *(const u32x4*)(Bch + 3072 + bo1);

        #pragma unroll
        for (int sj = 0; sj < 2; ++sj) {
            const u32x4 Ph = sj ? cPh1 : cPh0;
            const u32x4 Pl = sj ? cPl1 : cPl0;
            u32x4 Qh, Ql;
            #pragma unroll
            for (int r = 0; r < 4; ++r) {
                Qh[r] = rot16(Ph[r]) ^ 0x00008000u;     // (sb, cb)
                Ql[r] = rot16(Pl[r]) ^ 0x00008000u;
            }
            #pragma unroll
            for (int si = 0; si < 2; ++si) {
                const u32x4 Eh = si ? cEh1 : cEh0;
                const u32x4 El = si ? cEl1 : cEl0;
                accRe[si][sj] = mfma_bf16(Eh, Ph, accRe[si][sj]);
                accRe[si][sj] = mfma_bf16(Eh, Pl, accRe[si][sj]);
                accRe[si][sj] = mfma_bf16(El, Ph, accRe[si][sj]);
                accIm[si][sj] = mfma_bf16(Eh, Qh, accIm[si][sj]);
                accIm[si][sj] = mfma_bf16(Eh, Ql, accIm[si][sj]);
                accIm[si][sj] = mfma_bf16(El, Qh, accIm[si][sj]);
            }
        }
        cEh0 = nEh0; cEh1 = nEh1; cEl0 = nEl0; cEl1 = nEl1;
        cPh0 = nPh0; cPh1 = nPh1; cPl0 = nPl0; cPl1 = nPl1;
    }
    // final chunk compute
    #pragma unroll
    for (int sj = 0; sj < 2; ++sj) {
        const u32x4 Ph = sj ? cPh1 : cPh0;
        const u32x4 Pl = sj ? cPl1 : cPl0;
        u32x4 Qh, Ql;
        #pragma unroll
        for (int r = 0; r < 4; ++r) {
            Qh[r] = rot16(Ph[r]) ^ 0x00008000u;
            Ql[r] = rot16(Pl[r]) ^ 0x00008000u;
        }
        #pragma unroll
        for (int si = 0; si < 2; ++si) {
            const u32x4 Eh = si ? cEh1 : cEh0;
            const u32x4 El = si ? cEl1 : cEl0;
            accRe[si][sj] = mfma_bf16(Eh, Ph, accRe[si][sj]);
            accRe[si][sj] = mfma_bf16(Eh, Pl, accRe[si][sj]);
            accRe[si][sj] = mfma_bf16(El, Ph, accRe[si][sj]);
            accIm[si][sj] = mfma_bf16(Eh, Qh, accIm[si][sj]);
            accIm[si][sj] = mfma_bf16(Eh, Ql, accIm[si][sj]);
            accIm[si][sj] = mfma_bf16(El, Qh, accIm[si][sj]);
        }
    }

    // epilogue: direct global atomics into partial image (r8-verified mapping)
    #pragma unroll
    for (int si = 0; si < 2; ++si)
        #pragma unroll
        for (int sj = 0; sj < 2; ++sj)
            #pragma unroll
            for (int rg = 0; rg < 4; ++rg) {
                const int x = x0 + si * 16 + qd * 4 + rg;   // C/D row
                const int y = y0 + sj * 16 + l15;           // C/D col
                atomicAdd(outRe + x * NPIX + y, accRe[si][sj][rg]);
                atomicAdd(outIm + x * NPIX + y, accIm[si][sj][rg]);
            }
}

// ---------------------------------------------------------------------------
// fwdq: q[m] = sum_x A[m,x] * (sum_y B[m,y]*g[x,y]).   (unchanged from r5)
__device__ __forceinline__ void fw_stage_load(const unsigned* __restrict__ Ghi,
                                              const unsigned* __restrict__ Glo,
                                              int tid, int koff, u32x4 st[3]) {
    #pragma unroll
    for (int j = 0; j < 3; ++j) {
        const int li = tid + j * 576;
        if (li < 1536) {
            const int row = li >> 3, pl = (li >> 2) & 1, qt = li & 3;
            const unsigned* src = pl ? Glo : Ghi;
            st[j] = *(const u32x4*)(src + row * 192 + koff + qt * 4);
        }
    }
}
__device__ __forceinline__ void fw_stage_write(unsigned* sb, int tid, const u32x4 st[3]) {
    #pragma unroll
    for (int j = 0; j < 3; ++j) {
        const int li = tid + j * 576;
        if (li < 1536) {
            const int row = li >> 3, pl = (li >> 2) & 1, qt = li & 3;
            *(u32x4*)(sb + pl * 3840 + row * 20 + qt * 4) = st[j];
        }
    }
}

__global__ __launch_bounds__(576) void fwdq_k(
    const float* __restrict__ traj,
    const unsigned* __restrict__ Ghi, const unsigned* __restrict__ Glo,
    float* __restrict__ wre, float* __restrict__ wim,
    const int mode,
    float* __restrict__ qre, float* __restrict__ qim)
{
    __shared__ unsigned sG[2][2 * 3840];   // 60 KB
    const int tid = threadIdx.x;
    const int lane = tid & 63, wid = tid >> 6;         // wid 0..8
    const int l15 = lane & 15, q = lane >> 4;
    const int m = (blockIdx.x * 9 + wid) * 16 + l15;
    const float2 kk = *(const float2*)(traj + 2 * m);
    float kxh, kxl, kyh, kyl;
    ksplit(kk.x, kxh, kxl);
    ksplit(kk.y, kyh, kyl);

    f32x4 tre[12], tim[12];
    #pragma unroll
    for (int i = 0; i < 12; ++i) {
        tre[i] = (f32x4){0.f, 0.f, 0.f, 0.f};
        tim[i] = (f32x4){0.f, 0.f, 0.f, 0.f};
    }

    float bc, bs;
    { const float ph = redphase(kyh, kyl, (float)(q * 4 - 96)); 
      bc = __builtin_amdgcn_cosf(ph); bs = __builtin_amdgcn_sinf(ph); }
    const float r1c = __builtin_amdgcn_cosf(kk.y), r1s = __builtin_amdgcn_sinf(kk.y);
    float r16c, r16s;
    { float g = kk.y * 16.f; g -= rintf(g);
      r16c = __builtin_amdgcn_cosf(g); r16s = __builtin_amdgcn_sinf(g); }

    u32x4 st[3];
    fw_stage_load(Ghi, Glo, tid, 0, st);
    fw_stage_write(&sG[0][0], tid, st);
    __syncthreads();

    for (int ch = 0; ch < 12; ++ch) {
        if (ch < 11) fw_stage_load(Ghi, Glo, tid, (ch + 1) * 16, st);

        u32x4 Ph, Pl, Qh, Ql;
        {
            float c = bc, s = bs;
            #pragma unroll
            for (int r = 0; r < 4; ++r) {
                unsigned h, l; split_pk(c, s, h, l);
                Ph[r] = h; Pl[r] = l;
                Qh[r] = rot16(h) ^ 0x00008000u;
                Ql[r] = rot16(l) ^ 0x00008000u;
                const float nc = c * r1c - s * r1s, ns = s * r1c + c * r1s;
                c = nc; s = ns;
            }
            const float nbc = bc * r16c - bs * r16s, nbs = bs * r16c + bc * r16s;
            bc = nbc; bs = nbs;
        }

        const unsigned* sb = &sG[ch & 1][0];
        #pragma unroll
        for (int si = 0; si < 12; ++si) {
            const int base = (si * 16 + l15) * 20 + q * 4;
            const u32x4 gh = *(const u32x4*)(sb + base);
            const u32x4 gl = *(const u32x4*)(sb + 3840 + base);
            tre[si] = mfma_bf16(gh, Ph, tre[si]);
            tre[si] = mfma_bf16(gh, Pl, tre[si]);
            tre[si] = mfma_bf16(gl, Ph, tre[si]);
            tim[si] = mfma_bf16(gh, Qh, tim[si]);
            tim[si] = mfma_bf16(gh, Ql, tim[si]);
            tim[si] = mfma_bf16(gl, Qh, tim[si]);
        }

        if (ch < 11) {
            __syncthreads();
            fw_stage_write(&sG[(ch + 1) & 1][0], tid, st);
            __syncthreads();
        }
    }

    float qr = 0.f, qi = 0.f;
    {
        float g = kk.x * 16.f; g -= rintf(g);
        const float rc = __builtin_amdgcn_cosf(g), rs = __builtin_amdgcn_sinf(g);
        #pragma unroll
        for (int rg = 0; rg < 4; ++rg) {
            const float ph = redphase(kxh, kxl, (float)(q * 4 + rg - 96));
            float c = __builtin_amdgcn_cosf(ph), s = __builtin_amdgcn_sinf(ph);
            #pragma unroll
            for (int si = 0; si < 12; ++si) {
                const float tr = tre[si][rg], ti = tim[si][rg];
                qr += c * tr + s * ti;
                qi += c * ti - s * tr;
                const float nc = c * rc - s * rs, ns = s * rc + c * rs;
                c = nc; s = ns;
            }
        }
    }
    qr += __shfl_xor(qr, 16); qi += __shfl_xor(qi, 16);
    qr += __shfl_xor(qr, 32); qi += __shfl_xor(qi, 32);
    if (lane < 16) {
        if (mode == 0) {
            const float den = fmaxf(sqrtf(qr * qr + qi * qi), 1e-20f);
            wre[m] /= den; wim[m] /= den;
        } else {
            const float sc = sqrtf(wre[m] * wre[m] + wim[m] * wim[m]);
            qre[m] = qr * sc; qim[m] = qi * sc;
        }
    }
}

// ---------------------------------------------------------------------------
__global__ void presplit_k(const float* __restrict__ re, const float* __restrict__ im,
                           unsigned* __restrict__ Gh, unsigned* __restrict__ Gl) {
    const int e = blockIdx.x * 256 + threadIdx.x;
    unsigned h, l;
    split_pk(re[e], im[e], h, l);     // low16 = re (even K), high16 = im (odd K)
    Gh[e] = h; Gl[e] = l;
}

// Reduce PG partial images + presplit (pipe path)
__global__ void presplitP_k(const float* __restrict__ outP,
                            unsigned* __restrict__ Gh, unsigned* __restrict__ Gl) {
    const int e = blockIdx.x * 256 + threadIdx.x;
    float re = 0.f, im = 0.f;
    #pragma unroll
    for (int g = 0; g < PG; ++g) {
        re += outP[(size_t)g * (2 * MTOT) + e];
        im += outP[(size_t)g * (2 * MTOT) + MTOT + e];
    }
    unsigned h, l;
    split_pk(re, im, h, l);
    Gh[e] = h; Gl[e] = l;
}

// Reduce PG partial images -> final output
__global__ void reduceOut_k(const float* __restrict__ outP, float* __restrict__ out) {
    const int e = blockIdx.x * 256 + threadIdx.x;
    float re = 0.f, im = 0.f;
    #pragma unroll
    for (int g = 0; g < PG; ++g) {
        re += outP[(size_t)g * (2 * MTOT) + e];
        im += outP[(size_t)g * (2 * MTOT) + MTOT + e];
    }
    out[e] = re; out[MTOT + e] = im;
}

// ---------------------------------------------------------------------------
extern "C" void kernel_launch(void* const* d_in, const int* in_sizes, int n_in,
                              void* d_out, int out_size, void* d_ws, size_t ws_size,
                              hipStream_t stream)
{
    const float* xin  = (const float*)d_in[0];   // (2,192,192)
    const float* traj = (const float*)d_in[1];   // (36864,2)
    float* out = (float*)d_out;                  // (2,192,192)

    char* pb = (char*)d_ws;
    unsigned* BS = (unsigned*)pb; pb += (size_t)2304 * 6144 * 4;   // 56.6 MB
    unsigned* ES = (unsigned*)pb; pb += (size_t)2304 * 6144 * 4;   // 56.6 MB
    float* outP = (float*)pb; pb += (size_t)PG * 2 * MTOT * 4;
    float* wr   = (float*)pb; pb += MTOT * 4;
    float* wi   = (float*)pb; pb += MTOT * 4;
    float* dre  = (float*)pb; pb += MTOT * 4;
    float* dim_ = (float*)pb; pb += MTOT * 4;
    unsigned* Ghi = (unsigned*)pb; pb += MTOT * 4;
    unsigned* Glo = (unsigned*)pb; pb += MTOT * 4;

    precompP_k<<<dim3(MTOT / 256, NPIX), 256, 0, stream>>>(traj, 1, BS);
    winit_k<<<MTOT / 256, 256, 0, stream>>>(wr, wi);

    for (int it = 0; it < 3; ++it) {
        hipMemsetAsync(outP, 0, (size_t)PG * 2 * MTOT * 4, stream);
        ebuild_k<<<dim3(MTOT / 256, NPIX), 256, 0, stream>>>(traj, wr, wi, ES);
        adj_gemm_k<<<9 * SPLITS, 256, 0, stream>>>(ES, BS, outP);
        presplitP_k<<<MTOT / 256, 256, 0, stream>>>(outP, Ghi, Glo);
        fwdq_k<<<256, 576, 0, stream>>>(traj, Ghi, Glo, wr, wi, 0, dre, dim_);
    }

    presplit_k<<<MTOT / 256, 256, 0, stream>>>(xin, xin + MTOT, Ghi, Glo);
    fwdq_k<<<256, 576, 0, stream>>>(traj, Ghi, Glo, wr, wi, 1, dre, dim_);
    hipMemsetAsync(outP, 0, (size_t)PG * 2 * MTOT * 4, stream);
    ebuild_k<<<dim3(MTOT / 256, NPIX), 256, 0, stream>>>(traj, dre, dim_, ES);
    adj_gemm_k<<<9 * SPLITS, 256, 0, stream>>>(ES, BS, outP);
    reduceOut_k<<<MTOT / 256, 256, 0, stream>>>(outP, out);
}

// Round 3
// 528.272 us; speedup vs baseline: 1.1071x; 1.1071x over previous
//
#include <hip/hip_runtime.h>
#include <math.h>

// Radial NUFFT + Pipe-Menon density compensation, MI355X (gfx950).
// bf16 MFMA (16x16x32), 2-term hi/lo split (3 products). Round 17: r16's
// barrier-free adj_gemm with the software pipeline made UN-COLLAPSIBLE:
// 2x-unrolled loop with two named register sets Ra/Rb (no copies for the
// compiler to propagate away), sched_barrier(0) pinning each 8-load set
// above the following 24-MFMA compute. r16's VGPR_Count=52 proved the
// compiler had merged cur/nxt and serialized issue->latency->compute
// (78us, MfmaUtil 16%). 1-wave blocks (64 thr): zero inter-wave coupling,
// 4608 blocks, launch_bounds(64,4) -> ~122 regs -> 4 waves/SIMD TLP.

#define MTOT 36864      // N_SHOTS*N_SAMPLES == NPIX*NPIX
#define NPIX 192
#define SPLITS 128
#define MPS (MTOT / SPLITS)     // 288 m per split
#define ADJ_CHUNKS (MPS / 16)   // 18 chunks of 16 m per split
#define PG 4                    // partial output images

typedef __attribute__((ext_vector_type(8))) short s16x8;
typedef __attribute__((ext_vector_type(4))) float f32x4;
typedef __attribute__((ext_vector_type(4))) unsigned u32x4;

__device__ __forceinline__ f32x4 mfma_bf16(u32x4 a, u32x4 b, f32x4 c) {
    return __builtin_amdgcn_mfma_f32_16x16x32_bf16(
        __builtin_bit_cast(s16x8, a), __builtin_bit_cast(s16x8, b), c, 0, 0, 0);
}

// Split (a,b) into packed bf16 pairs: hi = (bf16(a) | bf16(b)<<16), lo = residuals.
__device__ __forceinline__ void split_pk(float a, float b, unsigned &hi, unsigned &lo) {
    const unsigned ua = __float_as_uint(a), ub = __float_as_uint(b);
    const unsigned ha = (ua + 0x8000u) & 0xffff0000u;
    const unsigned hb = (ub + 0x8000u) & 0xffff0000u;
    hi = (ha >> 16) | hb;
    const float la = a - __uint_as_float(ha);
    const float lb = b - __uint_as_float(hb);
    lo = ((__float_as_uint(la) + 0x8000u) >> 16) |
         ((__float_as_uint(lb) + 0x8000u) & 0xffff0000u);
}

// k split into 12-bit hi + residual so kh*p (p integer, |p|<=96) is EXACT in fp32.
__device__ __forceinline__ void ksplit(float k, float &kh, float &kl) {
    kh = __uint_as_float(__float_as_uint(k) & 0xfffff000u);
    kl = k - kh;
}
__device__ __forceinline__ float redphase(float kh, float kl, float p) {
    float r = kh * p;
    r -= rintf(r);
    r = fmaf(kl, p, r);
    return r;                   // revolutions, |r| <= ~0.512
}
__device__ __forceinline__ unsigned rot16(unsigned v) {
    return __builtin_amdgcn_alignbit(v, v, 16);
}

// ---------------------------------------------------------------------------
// Precompute packed B phasor (cos, -sin) hi/lo, chunk-contiguous, PLAIN layout:
// PS[mc][plane][c(192)][mi(16)].
__global__ void precompP_k(const float* __restrict__ traj, const int comp,
                           unsigned* __restrict__ PS) {
    const int m = blockIdx.x * 256 + threadIdx.x;
    const int c = blockIdx.y;
    float kh, kl; ksplit(traj[2 * m + comp], kh, kl);
    const float ph = redphase(kh, kl, (float)(c - 96));
    const float co = __builtin_amdgcn_cosf(ph);
    const float si = __builtin_amdgcn_sinf(ph);
    unsigned h, l; split_pk(co, -si, h, l);
    const int mc = m >> 4, mi = m & 15;
    PS[(size_t)mc * 6144 + c * 16 + mi]        = h;
    PS[(size_t)mc * 6144 + 3072 + c * 16 + mi] = l;
}

// E[m,x] = conj(A[m,x]) * d[m], packed bf16 hi/lo, same plain layout.
__global__ void ebuild_k(const float* __restrict__ traj,
                         const float* __restrict__ dr, const float* __restrict__ di,
                         unsigned* __restrict__ ES) {
    const int m = blockIdx.x * 256 + threadIdx.x;
    const int c = blockIdx.y;                        // x coordinate
    float kh, kl; ksplit(traj[2 * m], kh, kl);
    const float ph = redphase(kh, kl, (float)(c - 96));
    const float co = __builtin_amdgcn_cosf(ph);
    const float si = __builtin_amdgcn_sinf(ph);
    const float dr_ = dr[m], di_ = di[m];
    const float Er = co * dr_ - si * di_;
    const float Ei = co * di_ + si * dr_;
    unsigned h, l; split_pk(Er, Ei, h, l);
    const int mc = m >> 4, mi = m & 15;
    ES[(size_t)mc * 6144 + c * 16 + mi]        = h;
    ES[(size_t)mc * 6144 + 3072 + c * 16 + mi] = l;
}

__global__ void winit_k(float* __restrict__ wr, float* __restrict__ wi) {
    const int m = blockIdx.x * 256 + threadIdx.x;
    wr[m] = 1.f; wi[m] = 0.f;
}

// ---------------------------------------------------------------------------
// Adjoint pure GEMM: out[x,y] += sum_m E[m,x]*conj(B[m,y]).
// 1-wave blocks, barrier-free, register double-buffer Ra/Rb (structural).
__global__ __launch_bounds__(64, 4) void adj_gemm_k(
    const unsigned* __restrict__ ES, const unsigned* __restrict__ BS,
    float* __restrict__ outP)
{
    const int lane = threadIdx.x & 63;
    const int l15 = lane & 15, qd = lane >> 4;
    const int L = blockIdx.x;                      // 0..4607, XCD swizzle
    const int xcd = L & 7, j = L >> 3;             // j 0..575
    const int s = xcd * (SPLITS / 8) + j / 36;     // split 0..127
    const int r = j % 36;                          // 9 tiles x 4 waves
    const int tile = r >> 2, wid = r & 3;
    const int bx = tile % 3, by = tile / 3;
    const int wi = wid & 1, wj = wid >> 1;
    const int x0 = bx * 64 + wi * 32, y0 = by * 64 + wj * 32;
    float* outRe = outP + (size_t)(s & (PG - 1)) * (2 * MTOT);
    float* outIm = outRe + MTOT;

    // lane word-offsets of the 16B fragment loads within a chunk
    const int eo0 = (x0 + l15) * 16 + qd * 4;
    const int eo1 = (x0 + 16 + l15) * 16 + qd * 4;
    const int bo0 = (y0 + l15) * 16 + qd * 4;
    const int bo1 = (y0 + 16 + l15) * 16 + qd * 4;

    const unsigned* Ep = ES + (size_t)(s * ADJ_CHUNKS) * 6144;
    const unsigned* Bp = BS + (size_t)(s * ADJ_CHUNKS) * 6144;

    f32x4 accRe[2][2], accIm[2][2];
    #pragma unroll
    for (int i = 0; i < 2; ++i)
        #pragma unroll
        for (int j2 = 0; j2 < 2; ++j2) {
            accRe[i][j2] = (f32x4){0.f, 0.f, 0.f, 0.f};
            accIm[i][j2] = (f32x4){0.f, 0.f, 0.f, 0.f};
        }

    u32x4 Ra[8], Rb[8];

#define LOADSET(R)                                          \
    R[0] = *(const u32x4*)(Ep + eo0);                       \
    R[1] = *(const u32x4*)(Ep + eo1);                       \
    R[2] = *(const u32x4*)(Ep + 3072 + eo0);                \
    R[3] = *(const u32x4*)(Ep + 3072 + eo1);                \
    R[4] = *(const u32x4*)(Bp + bo0);                       \
    R[5] = *(const u32x4*)(Bp + bo1);                       \
    R[6] = *(const u32x4*)(Bp + 3072 + bo0);                \
    R[7] = *(const u32x4*)(Bp + 3072 + bo1);

#define COMPUTE(R)                                                         \
    {                                                                      \
        _Pragma("unroll")                                                  \
        for (int sj = 0; sj < 2; ++sj) {                                   \
            const u32x4 Ph = R[4 + sj];                                    \
            const u32x4 Pl = R[6 + sj];                                    \
            u32x4 Qh, Ql;                                                  \
            _Pragma("unroll")                                              \
            for (int rr = 0; rr < 4; ++rr) {                               \
                Qh[rr] = rot16(Ph[rr]) ^ 0x00008000u;                      \
                Ql[rr] = rot16(Pl[rr]) ^ 0x00008000u;                      \
            }                                                              \
            _Pragma("unroll")                                              \
            for (int si = 0; si < 2; ++si) {                               \
                const u32x4 Eh = R[si];                                    \
                const u32x4 El = R[2 + si];                                \
                accRe[si][sj] = mfma_bf16(Eh, Ph, accRe[si][sj]);          \
                accRe[si][sj] = mfma_bf16(Eh, Pl, accRe[si][sj]);          \
                accRe[si][sj] = mfma_bf16(El, Ph, accRe[si][sj]);          \
                accIm[si][sj] = mfma_bf16(Eh, Qh, accIm[si][sj]);          \
                accIm[si][sj] = mfma_bf16(Eh, Ql, accIm[si][sj]);          \
                accIm[si][sj] = mfma_bf16(El, Qh, accIm[si][sj]);          \
            }                                                              \
        }                                                                  \
    }

    LOADSET(Ra);                                   // chunk 0
    #pragma unroll 1
    for (int it = 0; it < (ADJ_CHUNKS - 2) / 2; ++it) {   // 8 iterations
        Ep += 6144; Bp += 6144;
        LOADSET(Rb);                               // chunk 2it+1
        __builtin_amdgcn_sched_barrier(0);
        COMPUTE(Ra);                               // chunk 2it
        Ep += 6144; Bp += 6144;
        LOADSET(Ra);                               // chunk 2it+2
        __builtin_amdgcn_sched_barrier(0);
        COMPUTE(Rb);                               // chunk 2it+1
    }
    Ep += 6144; Bp += 6144;
    LOADSET(Rb);                                   // chunk 17
    __builtin_amdgcn_sched_barrier(0);
    COMPUTE(Ra);                                   // chunk 16
    __builtin_amdgcn_sched_barrier(0);
    COMPUTE(Rb);                                   // chunk 17

#undef LOADSET
#undef COMPUTE

    // epilogue: direct global atomics into partial image (r8-verified mapping)
    #pragma unroll
    for (int si = 0; si < 2; ++si)
        #pragma unroll
        for (int sj = 0; sj < 2; ++sj)
            #pragma unroll
            for (int rg = 0; rg < 4; ++rg) {
                const int x = x0 + si * 16 + qd * 4 + rg;   // C/D row
                const int y = y0 + sj * 16 + l15;           // C/D col
                atomicAdd(outRe + x * NPIX + y, accRe[si][sj][rg]);
                atomicAdd(outIm + x * NPIX + y, accIm[si][sj][rg]);
            }
}

// ---------------------------------------------------------------------------
// fwdq: q[m] = sum_x A[m,x] * (sum_y B[m,y]*g[x,y]).   (unchanged from r5)
__device__ __forceinline__ void fw_stage_load(const unsigned* __restrict__ Ghi,
                                              const unsigned* __restrict__ Glo,
                                              int tid, int koff, u32x4 st[3]) {
    #pragma unroll
    for (int j = 0; j < 3; ++j) {
        const int li = tid + j * 576;
        if (li < 1536) {
            const int row = li >> 3, pl = (li >> 2) & 1, qt = li & 3;
            const unsigned* src = pl ? Glo : Ghi;
            st[j] = *(const u32x4*)(src + row * 192 + koff + qt * 4);
        }
    }
}
__device__ __forceinline__ void fw_stage_write(unsigned* sb, int tid, const u32x4 st[3]) {
    #pragma unroll
    for (int j = 0; j < 3; ++j) {
        const int li = tid + j * 576;
        if (li < 1536) {
            const int row = li >> 3, pl = (li >> 2) & 1, qt = li & 3;
            *(u32x4*)(sb + pl * 3840 + row * 20 + qt * 4) = st[j];
        }
    }
}

__global__ __launch_bounds__(576) void fwdq_k(
    const float* __restrict__ traj,
    const unsigned* __restrict__ Ghi, const unsigned* __restrict__ Glo,
    float* __restrict__ wre, float* __restrict__ wim,
    const int mode,
    float* __restrict__ qre, float* __restrict__ qim)
{
    __shared__ unsigned sG[2][2 * 3840];   // 60 KB
    const int tid = threadIdx.x;
    const int lane = tid & 63, wid = tid >> 6;         // wid 0..8
    const int l15 = lane & 15, q = lane >> 4;
    const int m = (blockIdx.x * 9 + wid) * 16 + l15;
    const float2 kk = *(const float2*)(traj + 2 * m);
    float kxh, kxl, kyh, kyl;
    ksplit(kk.x, kxh, kxl);
    ksplit(kk.y, kyh, kyl);

    f32x4 tre[12], tim[12];
    #pragma unroll
    for (int i = 0; i < 12; ++i) {
        tre[i] = (f32x4){0.f, 0.f, 0.f, 0.f};
        tim[i] = (f32x4){0.f, 0.f, 0.f, 0.f};
    }

    float bc, bs;
    { const float ph = redphase(kyh, kyl, (float)(q * 4 - 96)); 
      bc = __builtin_amdgcn_cosf(ph); bs = __builtin_amdgcn_sinf(ph); }
    const float r1c = __builtin_amdgcn_cosf(kk.y), r1s = __builtin_amdgcn_sinf(kk.y);
    float r16c, r16s;
    { float g = kk.y * 16.f; g -= rintf(g);
      r16c = __builtin_amdgcn_cosf(g); r16s = __builtin_amdgcn_sinf(g); }

    u32x4 st[3];
    fw_stage_load(Ghi, Glo, tid, 0, st);
    fw_stage_write(&sG[0][0], tid, st);
    __syncthreads();

    for (int ch = 0; ch < 12; ++ch) {
        if (ch < 11) fw_stage_load(Ghi, Glo, tid, (ch + 1) * 16, st);

        u32x4 Ph, Pl, Qh, Ql;
        {
            float c = bc, s = bs;
            #pragma unroll
            for (int r = 0; r < 4; ++r) {
                unsigned h, l; split_pk(c, s, h, l);
                Ph[r] = h; Pl[r] = l;
                Qh[r] = rot16(h) ^ 0x00008000u;
                Ql[r] = rot16(l) ^ 0x00008000u;
                const float nc = c * r1c - s * r1s, ns = s * r1c + c * r1s;
                c = nc; s = ns;
            }
            const float nbc = bc * r16c - bs * r16s, nbs = bs * r16c + bc * r16s;
            bc = nbc; bs = nbs;
        }

        const unsigned* sb = &sG[ch & 1][0];
        #pragma unroll
        for (int si = 0; si < 12; ++si) {
            const int base = (si * 16 + l15) * 20 + q * 4;
            const u32x4 gh = *(const u32x4*)(sb + base);
            const u32x4 gl = *(const u32x4*)(sb + 3840 + base);
            tre[si] = mfma_bf16(gh, Ph, tre[si]);
            tre[si] = mfma_bf16(gh, Pl, tre[si]);
            tre[si] = mfma_bf16(gl, Ph, tre[si]);
            tim[si] = mfma_bf16(gh, Qh, tim[si]);
            tim[si] = mfma_bf16(gh, Ql, tim[si]);
            tim[si] = mfma_bf16(gl, Qh, tim[si]);
        }

        if (ch < 11) {
            __syncthreads();
            fw_stage_write(&sG[(ch + 1) & 1][0], tid, st);
            __syncthreads();
        }
    }

    float qr = 0.f, qi = 0.f;
    {
        float g = kk.x * 16.f; g -= rintf(g);
        const float rc = __builtin_amdgcn_cosf(g), rs = __builtin_amdgcn_sinf(g);
        #pragma unroll
        for (int rg = 0; rg < 4; ++rg) {
            const float ph = redphase(kxh, kxl, (float)(q * 4 + rg - 96));
            float c = __builtin_amdgcn_cosf(ph), s = __builtin_amdgcn_sinf(ph);
            #pragma unroll
            for (int si = 0; si < 12; ++si) {
                const float tr = tre[si][rg], ti = tim[si][rg];
                qr += c * tr + s * ti;
                qi += c * ti - s * tr;
                const float nc = c * rc - s * rs, ns = s * rc + c * rs;
                c = nc; s = ns;
            }
        }
    }
    qr += __shfl_xor(qr, 16); qi += __shfl_xor(qi, 16);
    qr += __shfl_xor(qr, 32); qi += __shfl_xor(qi, 32);
    if (lane < 16) {
        if (mode == 0) {
            const float den = fmaxf(sqrtf(qr * qr + qi * qi), 1e-20f);
            wre[m] /= den; wim[m] /= den;
        } else {
            const float sc = sqrtf(wre[m] * wre[m] + wim[m] * wim[m]);
            qre[m] = qr * sc; qim[m] = qi * sc;
        }
    }
}

// ---------------------------------------------------------------------------
__global__ void presplit_k(const float* __restrict__ re, const float* __restrict__ im,
                           unsigned* __restrict__ Gh, unsigned* __restrict__ Gl) {
    const int e = blockIdx.x * 256 + threadIdx.x;
    unsigned h, l;
    split_pk(re[e], im[e], h, l);     // low16 = re (even K), high16 = im (odd K)
    Gh[e] = h; Gl[e] = l;
}

// Reduce PG partial images + presplit (pipe path)
__global__ void presplitP_k(const float* __restrict__ outP,
                            unsigned* __restrict__ Gh, unsigned* __restrict__ Gl) {
    const int e = blockIdx.x * 256 + threadIdx.x;
    float re = 0.f, im = 0.f;
    #pragma unroll
    for (int g = 0; g < PG; ++g) {
        re += outP[(size_t)g * (2 * MTOT) + e];
        im += outP[(size_t)g * (2 * MTOT) + MTOT + e];
    }
    unsigned h, l;
    split_pk(re, im, h, l);
    Gh[e] = h; Gl[e] = l;
}

// Reduce PG partial images -> final output
__global__ void reduceOut_k(const float* __restrict__ outP, float* __restrict__ out) {
    const int e = blockIdx.x * 256 + threadIdx.x;
    float re = 0.f, im = 0.f;
    #pragma unroll
    for (int g = 0; g < PG; ++g) {
        re += outP[(size_t)g * (2 * MTOT) + e];
        im += outP[(size_t)g * (2 * MTOT) + MTOT + e];
    }
    out[e] = re; out[MTOT + e] = im;
}

// ---------------------------------------------------------------------------
extern "C" void kernel_launch(void* const* d_in, const int* in_sizes, int n_in,
                              void* d_out, int out_size, void* d_ws, size_t ws_size,
                              hipStream_t stream)
{
    const float* xin  = (const float*)d_in[0];   // (2,192,192)
    const float* traj = (const float*)d_in[1];   // (36864,2)
    float* out = (float*)d_out;                  // (2,192,192)

    char* pb = (char*)d_ws;
    unsigned* BS = (unsigned*)pb; pb += (size_t)2304 * 6144 * 4;   // 56.6 MB
    unsigned* ES = (unsigned*)pb; pb += (size_t)2304 * 6144 * 4;   // 56.6 MB
    float* outP = (float*)pb; pb += (size_t)PG * 2 * MTOT * 4;
    float* wr   = (float*)pb; pb += MTOT * 4;
    float* wi   = (float*)pb; pb += MTOT * 4;
    float* dre  = (float*)pb; pb += MTOT * 4;
    float* dim_ = (float*)pb; pb += MTOT * 4;
    unsigned* Ghi = (unsigned*)pb; pb += MTOT * 4;
    unsigned* Glo = (unsigned*)pb; pb += MTOT * 4;

    precompP_k<<<dim3(MTOT / 256, NPIX), 256, 0, stream>>>(traj, 1, BS);
    winit_k<<<MTOT / 256, 256, 0, stream>>>(wr, wi);

    for (int it = 0; it < 3; ++it) {
        hipMemsetAsync(outP, 0, (size_t)PG * 2 * MTOT * 4, stream);
        ebuild_k<<<dim3(MTOT / 256, NPIX), 256, 0, stream>>>(traj, wr, wi, ES);
        adj_gemm_k<<<36 * SPLITS, 64, 0, stream>>>(ES, BS, outP);
        presplitP_k<<<MTOT / 256, 256, 0, stream>>>(outP, Ghi, Glo);
        fwdq_k<<<256, 576, 0, stream>>>(traj, Ghi, Glo, wr, wi, 0, dre, dim_);
    }

    presplit_k<<<MTOT / 256, 256, 0, stream>>>(xin, xin + MTOT, Ghi, Glo);
    fwdq_k<<<256, 576, 0, stream>>>(traj, Ghi, Glo, wr, wi, 1, dre, dim_);
    hipMemsetAsync(outP, 0, (size_t)PG * 2 * MTOT * 4, stream);
    ebuild_k<<<dim3(MTOT / 256, NPIX), 256, 0, stream>>>(traj, dre, dim_, ES);
    adj_gemm_k<<<36 * SPLITS, 64, 0, stream>>>(ES, BS, outP);
    reduceOut_k<<<MTOT / 256, 256, 0, stream>>>(outP, out);
}

// Round 4
// 463.184 us; speedup vs baseline: 1.2627x; 1.1405x over previous
//
#include <hip/hip_runtime.h>
#include <math.h>

// Radial NUFFT + Pipe-Menon density compensation, MI355X (gfx950).
// bf16 MFMA (16x16x32), 2-term hi/lo split (3 products). Round 18: ATOMIC-FREE
// adjoint. Evidence r14-r17: WRITE_SIZE == 9.4M atomics x 4B in every round ->
// each device-scope atomicAdd is an RMW at the DRAM-level coherent point
// (per-XCD L2s non-coherent) == a ~35us floor no staging change could move.
// Fix: 64 privatized partial images (one per split-group {g,g+64}), each
// written EXCLUSIVELY by its 9 tile-blocks with plain coalesced stores.
// Compute engine = r15's best-measured K-loop (LDS triple-buffer, counted
// s_waitcnt vmcnt(8), pre-swizzled global layout, gload_lds 16B) extended to
// one continuous 36-chunk pipeline over both splits (branchless id jump).
// outP memsets deleted (images fully overwritten).

#define MTOT 36864      // N_SHOTS*N_SAMPLES == NPIX*NPIX
#define NPIX 192
#define SPLITS 128
#define GRP 64                  // split-groups: block g covers splits {g, g+64}
#define NCH 36                  // 2 splits x 18 chunks of 16 m
#define PG 64                   // privatized partial images (one per group)

typedef __attribute__((ext_vector_type(8))) short s16x8;
typedef __attribute__((ext_vector_type(4))) float f32x4;
typedef __attribute__((ext_vector_type(4))) unsigned u32x4;

__device__ __forceinline__ f32x4 mfma_bf16(u32x4 a, u32x4 b, f32x4 c) {
    return __builtin_amdgcn_mfma_f32_16x16x32_bf16(
        __builtin_bit_cast(s16x8, a), __builtin_bit_cast(s16x8, b), c, 0, 0, 0);
}

// async 16B/lane global->LDS (DMA); LDS dest = wave-uniform base + lane*16.
__device__ __forceinline__ void g2l16(const void* g, void* l) {
    __builtin_amdgcn_global_load_lds(
        (const __attribute__((address_space(1))) void*)g,
        (__attribute__((address_space(3))) void*)l, 16, 0, 0);
}

// Split (a,b) into packed bf16 pairs: hi = (bf16(a) | bf16(b)<<16), lo = residuals.
__device__ __forceinline__ void split_pk(float a, float b, unsigned &hi, unsigned &lo) {
    const unsigned ua = __float_as_uint(a), ub = __float_as_uint(b);
    const unsigned ha = (ua + 0x8000u) & 0xffff0000u;
    const unsigned hb = (ub + 0x8000u) & 0xffff0000u;
    hi = (ha >> 16) | hb;
    const float la = a - __uint_as_float(ha);
    const float lb = b - __uint_as_float(hb);
    lo = ((__float_as_uint(la) + 0x8000u) >> 16) |
         ((__float_as_uint(lb) + 0x8000u) & 0xffff0000u);
}

// k split into 12-bit hi + residual so kh*p (p integer, |p|<=96) is EXACT in fp32.
__device__ __forceinline__ void ksplit(float k, float &kh, float &kl) {
    kh = __uint_as_float(__float_as_uint(k) & 0xfffff000u);
    kl = k - kh;
}
__device__ __forceinline__ float redphase(float kh, float kl, float p) {
    float r = kh * p;
    r -= rintf(r);
    r = fmaf(kl, p, r);
    return r;                   // revolutions, |r| <= ~0.512
}
__device__ __forceinline__ unsigned rot16(unsigned v) {
    return __builtin_amdgcn_alignbit(v, v, 16);
}
__device__ __forceinline__ int swz(int c) {        // bank swizzle (r10-verified)
    return ((c ^ (c >> 2)) & 3) << 2;
}

// ---------------------------------------------------------------------------
// Precompute packed B phasor (cos, -sin) hi/lo, chunk-contiguous + swizzled:
// PS[mc][plane][c(192)][mi^swz(c)]  (r10-verified layout).
__global__ void precompP_k(const float* __restrict__ traj, const int comp,
                           unsigned* __restrict__ PS) {
    const int m = blockIdx.x * 256 + threadIdx.x;
    const int c = blockIdx.y;
    float kh, kl; ksplit(traj[2 * m + comp], kh, kl);
    const float ph = redphase(kh, kl, (float)(c - 96));
    const float co = __builtin_amdgcn_cosf(ph);
    const float si = __builtin_amdgcn_sinf(ph);
    unsigned h, l; split_pk(co, -si, h, l);
    const int mc = m >> 4, mi = (m & 15) ^ swz(c);
    PS[(size_t)mc * 6144 + c * 16 + mi]        = h;
    PS[(size_t)mc * 6144 + 3072 + c * 16 + mi] = l;
}

// E[m,x] = conj(A[m,x]) * d[m], packed bf16 hi/lo, same swizzled layout.
__global__ void ebuild_k(const float* __restrict__ traj,
                         const float* __restrict__ dr, const float* __restrict__ di,
                         unsigned* __restrict__ ES) {
    const int m = blockIdx.x * 256 + threadIdx.x;
    const int c = blockIdx.y;                        // x coordinate
    float kh, kl; ksplit(traj[2 * m], kh, kl);
    const float ph = redphase(kh, kl, (float)(c - 96));
    const float co = __builtin_amdgcn_cosf(ph);
    const float si = __builtin_amdgcn_sinf(ph);
    const float dr_ = dr[m], di_ = di[m];
    const float Er = co * dr_ - si * di_;
    const float Ei = co * di_ + si * dr_;
    unsigned h, l; split_pk(Er, Ei, h, l);
    const int mc = m >> 4, mi = (m & 15) ^ swz(c);
    ES[(size_t)mc * 6144 + c * 16 + mi]        = h;
    ES[(size_t)mc * 6144 + 3072 + c * 16 + mi] = l;
}

__global__ void winit_k(float* __restrict__ wr, float* __restrict__ wi) {
    const int m = blockIdx.x * 256 + threadIdx.x;
    wr[m] = 1.f; wi[m] = 0.f;
}

// ---------------------------------------------------------------------------
// Adjoint pure GEMM: outP[g][x,y] = sum_{m in splits g,g+64} E[m,x]*conj(B[m,y]).
// 576 blocks (64 groups x 9 tiles) of 4 waves; each block owns a 64x64 tile of
// image g EXCLUSIVELY -> plain stores, zero atomics. r15 pipeline: 3 LDS
// buffers, stage chunk ch+2 while computing ch, barrier#1 after counted
// vmcnt(8) (two stages stay in flight), barrier#2 after lgkmcnt(0) closes the
// WAR on buf reuse. 36 continuous chunks; chunk id jumps +1134 at the split
// boundary (s = g+64), so the pipeline never drains mid-block.
__global__ __launch_bounds__(256) void adj_gemm_k(
    const unsigned* __restrict__ ES, const unsigned* __restrict__ BS,
    float* __restrict__ outP)
{
    __shared__ unsigned sAB[3][4096];              // 48 KB triple buffer
    const int tid = threadIdx.x;
    const int lane = tid & 63, wid = tid >> 6;     // wid 0..3
    const int l15 = lane & 15, qd = lane >> 4;
    const int L = blockIdx.x;                      // 0..575, XCD swizzle
    const int xcd = L & 7, j = L >> 3;             // j 0..71
    const int g = xcd * (GRP / 8) + j / 9;         // split-group 0..63
    const int tile = j % 9;
    const int bx = tile % 3, by = tile / 3;
    const int wi = wid & 1, wj = wid >> 1;
    const int x0 = bx * 64 + wi * 32, y0 = by * 64 + wj * 32;
    float* outRe = outP + (size_t)g * (2 * MTOT);
    float* outIm = outRe + MTOT;

    f32x4 accRe[2][2], accIm[2][2];
    #pragma unroll
    for (int i = 0; i < 2; ++i)
        #pragma unroll
        for (int j2 = 0; j2 < 2; ++j2) {
            accRe[i][j2] = (f32x4){0.f, 0.f, 0.f, 0.f};
            accIm[i][j2] = (f32x4){0.f, 0.f, 0.f, 0.f};
        }

    // staging: chunk c of this block = split (g + 64*(c>=18)), local chunk c%18
    const size_t g18 = (size_t)g * 18;
    const int exo = bx * 1024 + tid * 4;           // E rows [bx*64..+64)
    const int byo = by * 1024 + tid * 4;           // B rows [by*64..+64)
    #define STAGE(c, buf)                                                  \
    {                                                                      \
        const size_t id_ = (g18 + (c) + (((c) >= 18) ? 1134 : 0)) * 6144; \
        const unsigned* E0_ = ES + id_;                                    \
        const unsigned* B0_ = BS + id_;                                    \
        g2l16(E0_ + exo,        &sAB[buf][tid * 4]);                       \
        g2l16(E0_ + 3072 + exo, &sAB[buf][1024 + tid * 4]);                \
        g2l16(B0_ + byo,        &sAB[buf][2048 + tid * 4]);                \
        g2l16(B0_ + 3072 + byo, &sAB[buf][3072 + tid * 4]);                \
    }

    // fragment LDS word offsets within a buffer (local coord; swz(local)==swz(global))
    int eoff[2], boff[2];
    #pragma unroll
    for (int t = 0; t < 2; ++t) {
        const int cE = wi * 32 + t * 16 + l15;     // local x coord 0..63
        eoff[t] = cE * 16 + ((qd ^ ((cE ^ (cE >> 2)) & 3)) << 2);
        const int cB = wj * 32 + t * 16 + l15;     // local y coord 0..63
        boff[t] = 2048 + cB * 16 + ((qd ^ ((cB ^ (cB >> 2)) & 3)) << 2);
    }

    STAGE(0, 0);                                   // prologue: chunks 0,1
    STAGE(1, 1);

    int rb = 0;                                    // read buffer = ch % 3
    for (int ch = 0; ch < NCH; ++ch) {
        if (ch + 2 < NCH) {                        // stage chunk ch+2
            const int wb = (rb + 2 >= 3) ? rb - 1 : rb + 2;   // (ch+2)%3
            STAGE(ch + 2, wb);
            // outstanding: ch(4), ch+1(4), ch+2(4); wait oldest 4 (chunk ch)
            asm volatile("s_waitcnt vmcnt(8)" ::: "memory");
        } else if (ch + 1 < NCH) {
            asm volatile("s_waitcnt vmcnt(4)" ::: "memory");
        } else {
            asm volatile("s_waitcnt vmcnt(0)" ::: "memory");
        }
        __builtin_amdgcn_s_barrier();              // buf rb ready block-wide

        const unsigned* sb = &sAB[rb][0];
        u32x4 Eh[2], El[2], PhA[2], PlA[2];
        #pragma unroll
        for (int t = 0; t < 2; ++t) {
            Eh[t]  = *(const u32x4*)(sb + eoff[t]);
            El[t]  = *(const u32x4*)(sb + 1024 + eoff[t]);
            PhA[t] = *(const u32x4*)(sb + boff[t]);
            PlA[t] = *(const u32x4*)(sb + 1024 + boff[t]);
        }
        asm volatile("s_waitcnt lgkmcnt(0)" ::: "memory");
        __builtin_amdgcn_sched_barrier(0);         // rule 18: pin MFMAs below
        __builtin_amdgcn_s_barrier();              // all waves done reading rb

        #pragma unroll
        for (int sj = 0; sj < 2; ++sj) {
            const u32x4 Ph = PhA[sj], Pl = PlA[sj];
            u32x4 Qh, Ql;
            #pragma unroll
            for (int r = 0; r < 4; ++r) {
                Qh[r] = rot16(Ph[r]) ^ 0x00008000u;                       // (sb, cb)
                Ql[r] = rot16(Pl[r]) ^ 0x00008000u;
            }
            #pragma unroll
            for (int si = 0; si < 2; ++si) {
                accRe[si][sj] = mfma_bf16(Eh[si], Ph, accRe[si][sj]);
                accRe[si][sj] = mfma_bf16(Eh[si], Pl, accRe[si][sj]);
                accRe[si][sj] = mfma_bf16(El[si], Ph, accRe[si][sj]);
                accIm[si][sj] = mfma_bf16(Eh[si], Qh, accIm[si][sj]);
                accIm[si][sj] = mfma_bf16(Eh[si], Ql, accIm[si][sj]);
                accIm[si][sj] = mfma_bf16(El[si], Qh, accIm[si][sj]);
            }
        }
        rb = (rb + 1 == 3) ? 0 : rb + 1;
    }
    #undef STAGE

    // epilogue: PLAIN stores -- block exclusively owns tile (g, x0.., y0..)
    #pragma unroll
    for (int si = 0; si < 2; ++si)
        #pragma unroll
        for (int sj = 0; sj < 2; ++sj)
            #pragma unroll
            for (int rg = 0; rg < 4; ++rg) {
                const int x = x0 + si * 16 + qd * 4 + rg;   // C/D row
                const int y = y0 + sj * 16 + l15;           // C/D col
                outRe[x * NPIX + y] = accRe[si][sj][rg];
                outIm[x * NPIX + y] = accIm[si][sj][rg];
            }
}

// ---------------------------------------------------------------------------
// fwdq: q[m] = sum_x A[m,x] * (sum_y B[m,y]*g[x,y]).   (unchanged from r5)
__device__ __forceinline__ void fw_stage_load(const unsigned* __restrict__ Ghi,
                                              const unsigned* __restrict__ Glo,
                                              int tid, int koff, u32x4 st[3]) {
    #pragma unroll
    for (int j = 0; j < 3; ++j) {
        const int li = tid + j * 576;
        if (li < 1536) {
            const int row = li >> 3, pl = (li >> 2) & 1, qt = li & 3;
            const unsigned* src = pl ? Glo : Ghi;
            st[j] = *(const u32x4*)(src + row * 192 + koff + qt * 4);
        }
    }
}
__device__ __forceinline__ void fw_stage_write(unsigned* sb, int tid, const u32x4 st[3]) {
    #pragma unroll
    for (int j = 0; j < 3; ++j) {
        const int li = tid + j * 576;
        if (li < 1536) {
            const int row = li >> 3, pl = (li >> 2) & 1, qt = li & 3;
            *(u32x4*)(sb + pl * 3840 + row * 20 + qt * 4) = st[j];
        }
    }
}

__global__ __launch_bounds__(576) void fwdq_k(
    const float* __restrict__ traj,
    const unsigned* __restrict__ Ghi, const unsigned* __restrict__ Glo,
    float* __restrict__ wre, float* __restrict__ wim,
    const int mode,
    float* __restrict__ qre, float* __restrict__ qim)
{
    __shared__ unsigned sG[2][2 * 3840];   // 60 KB
    const int tid = threadIdx.x;
    const int lane = tid & 63, wid = tid >> 6;         // wid 0..8
    const int l15 = lane & 15, q = lane >> 4;
    const int m = (blockIdx.x * 9 + wid) * 16 + l15;
    const float2 kk = *(const float2*)(traj + 2 * m);
    float kxh, kxl, kyh, kyl;
    ksplit(kk.x, kxh, kxl);
    ksplit(kk.y, kyh, kyl);

    f32x4 tre[12], tim[12];
    #pragma unroll
    for (int i = 0; i < 12; ++i) {
        tre[i] = (f32x4){0.f, 0.f, 0.f, 0.f};
        tim[i] = (f32x4){0.f, 0.f, 0.f, 0.f};
    }

    float bc, bs;
    { const float ph = redphase(kyh, kyl, (float)(q * 4 - 96)); 
      bc = __builtin_amdgcn_cosf(ph); bs = __builtin_amdgcn_sinf(ph); }
    const float r1c = __builtin_amdgcn_cosf(kk.y), r1s = __builtin_amdgcn_sinf(kk.y);
    float r16c, r16s;
    { float g = kk.y * 16.f; g -= rintf(g);
      r16c = __builtin_amdgcn_cosf(g); r16s = __builtin_amdgcn_sinf(g); }

    u32x4 st[3];
    fw_stage_load(Ghi, Glo, tid, 0, st);
    fw_stage_write(&sG[0][0], tid, st);
    __syncthreads();

    for (int ch = 0; ch < 12; ++ch) {
        if (ch < 11) fw_stage_load(Ghi, Glo, tid, (ch + 1) * 16, st);

        u32x4 Ph, Pl, Qh, Ql;
        {
            float c = bc, s = bs;
            #pragma unroll
            for (int r = 0; r < 4; ++r) {
                unsigned h, l; split_pk(c, s, h, l);
                Ph[r] = h; Pl[r] = l;
                Qh[r] = rot16(h) ^ 0x00008000u;
                Ql[r] = rot16(l) ^ 0x00008000u;
                const float nc = c * r1c - s * r1s, ns = s * r1c + c * r1s;
                c = nc; s = ns;
            }
            const float nbc = bc * r16c - bs * r16s, nbs = bs * r16c + bc * r16s;
            bc = nbc; bs = nbs;
        }

        const unsigned* sb = &sG[ch & 1][0];
        #pragma unroll
        for (int si = 0; si < 12; ++si) {
            const int base = (si * 16 + l15) * 20 + q * 4;
            const u32x4 gh = *(const u32x4*)(sb + base);
            const u32x4 gl = *(const u32x4*)(sb + 3840 + base);
            tre[si] = mfma_bf16(gh, Ph, tre[si]);
            tre[si] = mfma_bf16(gh, Pl, tre[si]);
            tre[si] = mfma_bf16(gl, Ph, tre[si]);
            tim[si] = mfma_bf16(gh, Qh, tim[si]);
            tim[si] = mfma_bf16(gh, Ql, tim[si]);
            tim[si] = mfma_bf16(gl, Qh, tim[si]);
        }

        if (ch < 11) {
            __syncthreads();
            fw_stage_write(&sG[(ch + 1) & 1][0], tid, st);
            __syncthreads();
        }
    }

    float qr = 0.f, qi = 0.f;
    {
        float g = kk.x * 16.f; g -= rintf(g);
        const float rc = __builtin_amdgcn_cosf(g), rs = __builtin_amdgcn_sinf(g);
        #pragma unroll
        for (int rg = 0; rg < 4; ++rg) {
            const float ph = redphase(kxh, kxl, (float)(q * 4 + rg - 96));
            float c = __builtin_amdgcn_cosf(ph), s = __builtin_amdgcn_sinf(ph);
            #pragma unroll
            for (int si = 0; si < 12; ++si) {
                const float tr = tre[si][rg], ti = tim[si][rg];
                qr += c * tr + s * ti;
                qi += c * ti - s * tr;
                const float nc = c * rc - s * rs, ns = s * rc + c * rs;
                c = nc; s = ns;
            }
        }
    }
    qr += __shfl_xor(qr, 16); qi += __shfl_xor(qi, 16);
    qr += __shfl_xor(qr, 32); qi += __shfl_xor(qi, 32);
    if (lane < 16) {
        if (mode == 0) {
            const float den = fmaxf(sqrtf(qr * qr + qi * qi), 1e-20f);
            wre[m] /= den; wim[m] /= den;
        } else {
            const float sc = sqrtf(wre[m] * wre[m] + wim[m] * wim[m]);
            qre[m] = qr * sc; qim[m] = qi * sc;
        }
    }
}

// ---------------------------------------------------------------------------
__global__ void presplit_k(const float* __restrict__ re, const float* __restrict__ im,
                           unsigned* __restrict__ Gh, unsigned* __restrict__ Gl) {
    const int e = blockIdx.x * 256 + threadIdx.x;
    unsigned h, l;
    split_pk(re[e], im[e], h, l);     // low16 = re (even K), high16 = im (odd K)
    Gh[e] = h; Gl[e] = l;
}

// Reduce PG partial images + presplit (pipe path)
__global__ void presplitP_k(const float* __restrict__ outP,
                            unsigned* __restrict__ Gh, unsigned* __restrict__ Gl) {
    const int e = blockIdx.x * 256 + threadIdx.x;
    float re = 0.f, im = 0.f;
    #pragma unroll 8
    for (int g = 0; g < PG; ++g) {
        re += outP[(size_t)g * (2 * MTOT) + e];
        im += outP[(size_t)g * (2 * MTOT) + MTOT + e];
    }
    unsigned h, l;
    split_pk(re, im, h, l);
    Gh[e] = h; Gl[e] = l;
}

// Reduce PG partial images -> final output
__global__ void reduceOut_k(const float* __restrict__ outP, float* __restrict__ out) {
    const int e = blockIdx.x * 256 + threadIdx.x;
    float re = 0.f, im = 0.f;
    #pragma unroll 8
    for (int g = 0; g < PG; ++g) {
        re += outP[(size_t)g * (2 * MTOT) + e];
        im += outP[(size_t)g * (2 * MTOT) + MTOT + e];
    }
    out[e] = re; out[MTOT + e] = im;
}

// ---------------------------------------------------------------------------
extern "C" void kernel_launch(void* const* d_in, const int* in_sizes, int n_in,
                              void* d_out, int out_size, void* d_ws, size_t ws_size,
                              hipStream_t stream)
{
    const float* xin  = (const float*)d_in[0];   // (2,192,192)
    const float* traj = (const float*)d_in[1];   // (36864,2)
    float* out = (float*)d_out;                  // (2,192,192)

    char* pb = (char*)d_ws;
    unsigned* BS = (unsigned*)pb; pb += (size_t)2304 * 6144 * 4;   // 56.6 MB
    unsigned* ES = (unsigned*)pb; pb += (size_t)2304 * 6144 * 4;   // 56.6 MB
    float* outP = (float*)pb; pb += (size_t)PG * 2 * MTOT * 4;     // 18.9 MB
    float* wr   = (float*)pb; pb += MTOT * 4;
    float* wi   = (float*)pb; pb += MTOT * 4;
    float* dre  = (float*)pb; pb += MTOT * 4;
    float* dim_ = (float*)pb; pb += MTOT * 4;
    unsigned* Ghi = (unsigned*)pb; pb += MTOT * 4;
    unsigned* Glo = (unsigned*)pb; pb += MTOT * 4;

    precompP_k<<<dim3(MTOT / 256, NPIX), 256, 0, stream>>>(traj, 1, BS);
    winit_k<<<MTOT / 256, 256, 0, stream>>>(wr, wi);

    for (int it = 0; it < 3; ++it) {
        ebuild_k<<<dim3(MTOT / 256, NPIX), 256, 0, stream>>>(traj, wr, wi, ES);
        adj_gemm_k<<<9 * GRP, 256, 0, stream>>>(ES, BS, outP);
        presplitP_k<<<MTOT / 256, 256, 0, stream>>>(outP, Ghi, Glo);
        fwdq_k<<<256, 576, 0, stream>>>(traj, Ghi, Glo, wr, wi, 0, dre, dim_);
    }

    presplit_k<<<MTOT / 256, 256, 0, stream>>>(xin, xin + MTOT, Ghi, Glo);
    fwdq_k<<<256, 576, 0, stream>>>(traj, Ghi, Glo, wr, wi, 1, dre, dim_);
    ebuild_k<<<dim3(MTOT / 256, NPIX), 256, 0, stream>>>(traj, dre, dim_, ES);
    adj_gemm_k<<<9 * GRP, 256, 0, stream>>>(ES, BS, outP);
    reduceOut_k<<<MTOT / 256, 256, 0, stream>>>(outP, out);
}